// Round 8
// baseline (136.215 us; speedup 1.0000x reference)
//
#include <hip/hip_runtime.h>
#include <hip/hip_bf16.h>
#include <stdint.h>

// ---------------------------------------------------------------------------
// QNN forward:
//   angles = x@W^T + b                                  (embed blocks of k_main)
//   E[b][i] = prod_w cs[w][bit_{9-w}(i)]   (product state after RY embedding)
//   Rows 0..783 of the fixed circuit unitary U, via ADJOINT simulation:
//     k_prep: build plan for U^dagger = prod_{l=19..0} [ring_l^-1 ; Rot_l^dag]
//             with CNOTs folded into GF(2) index-bit tracking and wire-pairs
//             fused into 4x4 complex matrices, pre-packed for v_pk_fma_f32.
//     k_main blocks 0..783: block p simulates U^dag|p> (100 quad passes over an
//             8KB LDS state, 256 thr, one s_barrier per pass), writes Bt rows
//             2p (Re) / 2p+1 (-Im) directly.
//     k_main blocks 784..8975: embed rows (grid filler -> hides usim latency).
//   out[b][p] = clip(|amp|^2 * 784, 0, 1)
//     -> one f16 MFMA GEMM C[8192][1664] = E @ Bt^T, 256x256 tile, BK=64,
//        2-phase pipeline with STAGE ISSUED BEFORE COMPUTE (loads fly under
//        MFMA; one __syncthreads per K-tile), T2 XOR LDS swizzle (pre-swizzled
//        global source + swizzled ds_read), |.|^2 epilogue fused via
//        shfl_xor(1), XCD-swizzled grid.
// ---------------------------------------------------------------------------

#define NWIRES  10
#define DIM     1024
#define NLAYERS 20
#define NGATES  200
#define NPASS   100
#define PIXELS  784
#define BATCH   8192

typedef _Float16 f16;
typedef _Float16 f16x8 __attribute__((ext_vector_type(8)));
typedef float    f32x4 __attribute__((ext_vector_type(4)));
typedef float    f32x2 __attribute__((ext_vector_type(2)));

typedef const __attribute__((address_space(1))) void* gas1_t;
typedef __attribute__((address_space(3))) void*       las3_t;

__device__ __forceinline__ void gload_lds16(const void* g, void* l) {
  __builtin_amdgcn_global_load_lds((gas1_t)g, (las3_t)l, 16, 0, 0);
}

// ---------------------------------------------------------------------------
// Kernel 1: ADJOINT plan precompute (1 block).
// ---------------------------------------------------------------------------
__global__ __launch_bounds__(256) void k_prep(const float* __restrict__ qw,
                                              float* __restrict__ plan_mat,
                                              unsigned* __restrict__ plan_idx,
                                              unsigned* __restrict__ plan_final) {
  __shared__ float gm[NGATES][8];   // adjoint Rot matrices (complex 2x2)
  const int tid = threadIdx.x;

  // Rot(phi,th,om)^dag entries:
  //   a00 = e^{+i(phi+om)/2} c    a01 = e^{+i(phi-om)/2} s
  //   a10 = -e^{-i(phi-om)/2} s   a11 = e^{-i(phi+om)/2} c
  if (tid < NGATES) {
    float phi = qw[tid * 3 + 0], th = qw[tid * 3 + 1], om = qw[tid * 3 + 2];
    float s, c, sa, ca, sb, cb;
    sincosf(0.5f * th, &s, &c);
    sincosf(0.5f * (phi + om), &sa, &ca);
    sincosf(0.5f * (phi - om), &sb, &cb);
    gm[tid][0] = ca * c;  gm[tid][1] = sa * c;    // a00
    gm[tid][2] = cb * s;  gm[tid][3] = sb * s;    // a01
    gm[tid][4] = -cb * s; gm[tid][5] = sb * s;    // a10
    gm[tid][6] = ca * c;  gm[tid][7] = -sa * c;   // a11
  }
  __syncthreads();

  if (tid == 0) {
    unsigned rowA[NWIRES], invc[NWIRES];
    for (int i = 0; i < NWIRES; i++) { rowA[i] = 1u << i; invc[i] = 1u << i; }
    for (int lrev = 0; lrev < NLAYERS; lrev++) {
      int l = NLAYERS - 1 - lrev;
      int r = (l % (NWIRES - 1)) + 1;
      // inverse ring: same CNOTs, applied w = 9 .. 0
      for (int w = NWIRES - 1; w >= 0; w--) {
        int c = w, t = (w + r) % NWIRES;
        int pc = 9 - c, pt = 9 - t;
        rowA[pt] ^= rowA[pc];
        invc[pc] ^= invc[pt];
      }
      for (int s = 0; s < 5; s++) {
        int w1 = 2 * s, w2 = 2 * s + 1;
        int p1 = 9 - w1, p2 = 9 - w2;
        unsigned u1 = rowA[p1], u2 = rowA[p2];
        unsigned m1 = invc[p1], m2 = invc[p2];
        // 2-row GF(2) elimination to echelon (b1 in u1 only, b2 in u2 only)
        unsigned b1 = u1 & (0u - u1);
        if (u2 & b1) u2 ^= u1;
        unsigned b2 = u2 & (0u - u2);
        if (u1 & b2) u1 ^= u2;
        unsigned bLo = (b1 < b2) ? b1 : b2;
        unsigned bHi = (b1 < b2) ? b2 : b1;
        unsigned* P = plan_idx + (size_t)(lrev * 5 + s) * 8;
        P[0] = bLo; P[1] = bHi; P[2] = u1; P[3] = u2;
        P[4] = b1;  P[5] = b2;  P[6] = m1; P[7] = m2;
      }
    }
    for (int p = 0; p < NWIRES; p++) plan_final[p] = invc[p];
  } else if (tid >= 100 && tid < 200) {
    int t = tid - 100;                 // pass index
    int lrev = t / 5, s = t % 5;
    int l = NLAYERS - 1 - lrev;
    int g1 = l * NWIRES + 2 * s, g2 = g1 + 1;
    float* K = plan_mat + (size_t)t * 64;
#pragma unroll
    for (int r = 0; r < 4; r++) {
#pragma unroll
      for (int c = 0; c < 4; c++) {
        int r1 = r >> 1, c1 = c >> 1, r2 = r & 1, c2 = c & 1;
        float ar = gm[g1][(r1 * 2 + c1) * 2], ai = gm[g1][(r1 * 2 + c1) * 2 + 1];
        float br = gm[g2][(r2 * 2 + c2) * 2], bi = gm[g2][(r2 * 2 + c2) * 2 + 1];
        float kr = ar * br - ai * bi;
        float ki = ar * bi + ai * br;
        float* e = K + (r * 4 + c) * 4;
        e[0] = kr; e[1] = kr; e[2] = -ki; e[3] = ki;   // packed for pk-FMA
      }
    }
  }
}

// ---------------------------------------------------------------------------
// Kernel 2 (fused): blocks 0..783 = usim column p; blocks 784.. = embed rows.
// ---------------------------------------------------------------------------
__global__ __launch_bounds__(256) void k_main(const float* __restrict__ plan_mat,
                                              const unsigned* __restrict__ plan_idx,
                                              const unsigned* __restrict__ plan_final,
                                              const float* __restrict__ x,
                                              const float* __restrict__ W,
                                              const float* __restrict__ bias,
                                              f16* __restrict__ E,
                                              f16* __restrict__ Bt) {
  __shared__ f32x2 st[DIM];          // usim state (8 KB)
  __shared__ float part[4][NWIRES];  // embed partials
  __shared__ float csh[NWIRES][2];   // embed cos/sin

  const int tid = threadIdx.x;

  if (blockIdx.x < PIXELS) {
    // ---------------- usim: simulate U^dag |col> ----------------
    const int col = blockIdx.x;

    for (int i = tid; i < DIM; i += 256)
      st[i] = (f32x2){i == col ? 1.f : 0.f, 0.f};
    __syncthreads();

    for (int t = 0; t < NPASS; t++) {
      const unsigned* P = plan_idx + (size_t)t * 8;
      const unsigned bLo = P[0], bHi = P[1], u1 = P[2], u2 = P[3];
      const unsigned pb1 = P[4], pb2 = P[5], m1 = P[6], m2 = P[7];
      const f32x4* Kp = (const f32x4*)(plan_mat + (size_t)t * 64);

      // coset representative: insert 0-bits at bLo,bHi, then fix both parities
      unsigned q  = (unsigned)tid;
      unsigned xx = ((q & ~(bLo - 1u)) << 1) | (q & (bLo - 1u));
      unsigned j0 = ((xx & ~(bHi - 1u)) << 1) | (xx & (bHi - 1u));
      unsigned j  = j0 ^ ((__popc(u1 & j0) & 1) ? pb1 : 0u)
                       ^ ((__popc(u2 & j0) & 1) ? pb2 : 0u);

      f32x2 v0 = st[j];
      f32x2 v1 = st[j ^ m2];
      f32x2 v2 = st[j ^ m1];
      f32x2 v3 = st[j ^ m1 ^ m2];
      f32x2 w0 = {v0.y, v0.x}, w1 = {v1.y, v1.x};
      f32x2 w2 = {v2.y, v2.x}, w3 = {v3.y, v3.x};

      f32x2 r0 = {0.f, 0.f}, r1 = {0.f, 0.f}, r2 = {0.f, 0.f}, r3 = {0.f, 0.f};
      // Kp[e] = (kr, kr, -ki, ki):  acc += (kr,kr)*v ; acc += (-ki,ki)*swap(v)
#define CM(rr, e, vv, ww)                         \
      { f32x4 kk = Kp[e];                         \
        rr += (f32x2){kk.x, kk.y} * (vv);         \
        rr += (f32x2){kk.z, kk.w} * (ww); }
      CM(r0, 0, v0, w0)  CM(r0, 1, v1, w1)  CM(r0, 2, v2, w2)  CM(r0, 3, v3, w3)
      CM(r1, 4, v0, w0)  CM(r1, 5, v1, w1)  CM(r1, 6, v2, w2)  CM(r1, 7, v3, w3)
      CM(r2, 8, v0, w0)  CM(r2, 9, v1, w1)  CM(r2, 10, v2, w2) CM(r2, 11, v3, w3)
      CM(r3, 12, v0, w0) CM(r3, 13, v1, w1) CM(r3, 14, v2, w2) CM(r3, 15, v3, w3)
#undef CM

      // In-place write of the SAME quad this thread read: disjoint across
      // threads, so no intra-pass hazard; one barrier separates passes.
      st[j]           = r0;
      st[j ^ m2]      = r1;
      st[j ^ m1]      = r2;
      st[j ^ m1 ^ m2] = r3;
      __syncthreads();
    }

    // logical amplitude i lives at storage j = XOR of inv columns of set bits;
    // U[p][i] = conj(st[j]).
    unsigned invl[NWIRES];
#pragma unroll
    for (int p = 0; p < NWIRES; p++) invl[p] = plan_final[p];

    __align__(8) f16 re4[4], im4[4];
#pragma unroll
    for (int u = 0; u < 4; u++) {
      int i = tid * 4 + u;
      unsigned j = 0;
#pragma unroll
      for (int p = 0; p < NWIRES; p++)
        if ((i >> p) & 1) j ^= invl[p];
      f32x2 v = st[j];
      re4[u] = (f16)v.x;
      im4[u] = (f16)(-v.y);
    }
    *(uint2*)(&Bt[(size_t)(2 * col) * DIM + tid * 4])     = *(const uint2*)re4;
    *(uint2*)(&Bt[(size_t)(2 * col + 1) * DIM + tid * 4]) = *(const uint2*)im4;
    return;
  }

  // ---------------- embed: linear layer + RY product state ----------------
  const int b = blockIdx.x - PIXELS;
  const float* xr = x + (size_t)b * PIXELS;

  float acc[NWIRES];
#pragma unroll
  for (int w = 0; w < NWIRES; w++) acc[w] = 0.f;

  for (int k = tid; k < PIXELS; k += 256) {
    float xv = xr[k];
#pragma unroll
    for (int w = 0; w < NWIRES; w++) acc[w] = fmaf(xv, W[w * PIXELS + k], acc[w]);
  }

#pragma unroll
  for (int w = 0; w < NWIRES; w++) {
    float v = acc[w];
#pragma unroll
    for (int off = 32; off > 0; off >>= 1) v += __shfl_xor(v, off, 64);
    acc[w] = v;
  }

  const int wv = tid >> 6, ln = tid & 63;
  if (ln == 0) {
#pragma unroll
    for (int w = 0; w < NWIRES; w++) part[wv][w] = acc[w];
  }
  __syncthreads();
  if (tid < NWIRES) {
    float a = part[0][tid] + part[1][tid] + part[2][tid] + part[3][tid] + bias[tid];
    float s, c;
    sincosf(0.5f * a, &s, &c);
    csh[tid][0] = c;
    csh[tid][1] = s;
  }
  __syncthreads();

  __align__(8) f16 e4[4];
#pragma unroll
  for (int u = 0; u < 4; u++) {
    int i = tid * 4 + u;
    float pr = 1.f;
#pragma unroll
    for (int w = 0; w < NWIRES; w++) pr *= csh[w][(i >> (9 - w)) & 1];
    e4[u] = (f16)pr;
  }
  *(uint2*)(&E[(size_t)b * DIM + tid * 4]) = *(const uint2*)e4;
}

// ---------------------------------------------------------------------------
// Kernel 3: C = E[8192][1024] @ Bt^T, f16 MFMA 16x16x32.
// 256x256 tile, BK=64, 512 threads (8 waves, 2M x 4N), 128 KB LDS dbuf.
// 2-phase pipeline done right: STAGE(next) issued BEFORE ds_read+MFMA of cur
// (HBM latency hides under ~310 cy of MFMA), ONE __syncthreads per K-tile.
// T2 swizzle: 16B-unit column c8 ^= (row&7), applied to the global SOURCE of
// global_load_lds (LDS dest stays linear) and to the ds_read address.
// Fused |re|^2+|im|^2 epilogue; XCD-swizzled flat grid (224 = 8 x 28).
// ---------------------------------------------------------------------------
__device__ __forceinline__ void g_stage(const f16* __restrict__ g, f16* l,
                                        int tid, int row0, int kt) {
#pragma unroll
  for (int r = 0; r < 4; r++) {
    int u   = r * 512 + tid;                 // 16B unit, 0..2047 (linear LDS)
    int row = u >> 3;
    int c8  = (u & 7) ^ (row & 7);           // inverse-swizzled source column
    gload_lds16((const char*)g + (size_t)(row0 + row) * 2048 + kt * 128 + c8 * 16,
                (char*)l + (size_t)u * 16);
  }
}

__global__ __launch_bounds__(512, 2) void k_gemm(const f16* __restrict__ E,
                                                 const f16* __restrict__ Bt,
                                                 float* __restrict__ out) {
  __shared__ __align__(16) f16 As[2][256 * 64];   // 64 KB
  __shared__ __align__(16) f16 Bs[2][256 * 64];   // 64 KB

  const int tid = threadIdx.x;                    // 0..511
  const int wid = tid >> 6, ln = tid & 63;
  const int wm = wid >> 2, wn = wid & 3;          // 2 x 4 wave grid

  const int bid = blockIdx.x;                     // 0..223 (32 mt x 7 nt)
  const int swz = (bid & 7) * 28 + (bid >> 3);    // XCD-contiguous chunks
  const int mt  = swz % 32, nt = swz / 32;
  const int m0  = mt * 256;
  const int n0  = nt * 256;

  f32x4 acc[8][4];
#pragma unroll
  for (int a = 0; a < 8; a++)
#pragma unroll
    for (int q = 0; q < 4; q++) acc[a][q] = (f32x4){0.f, 0.f, 0.f, 0.f};

  // swizzled ds_read element offset for logical (row R, kk, lane-quad)
#define SWZ_OFF(R, kk) ((R) * 64 + (((kk) * 4 + (ln >> 4)) ^ ((R) & 7)) * 8)

#define COMPUTE(buf)                                                            \
  {                                                                             \
    _Pragma("unroll")                                                           \
    for (int kk = 0; kk < 2; kk++) {                                            \
      f16x8 af[8], bf[4];                                                       \
      _Pragma("unroll")                                                         \
      for (int mi = 0; mi < 8; mi++) {                                          \
        int Ra = wm * 128 + mi * 16 + (ln & 15);                                \
        af[mi] = *(const f16x8*)&As[buf][SWZ_OFF(Ra, kk)];                      \
      }                                                                         \
      _Pragma("unroll")                                                         \
      for (int ni = 0; ni < 4; ni++) {                                          \
        int Rb = wn * 64 + ni * 16 + (ln & 15);                                 \
        bf[ni] = *(const f16x8*)&Bs[buf][SWZ_OFF(Rb, kk)];                      \
      }                                                                         \
      __builtin_amdgcn_s_setprio(1);                                            \
      _Pragma("unroll")                                                         \
      for (int mi = 0; mi < 8; mi++)                                            \
        _Pragma("unroll")                                                       \
        for (int ni = 0; ni < 4; ni++)                                          \
          acc[mi][ni] = __builtin_amdgcn_mfma_f32_16x16x32_f16(                 \
              af[mi], bf[ni], acc[mi][ni], 0, 0, 0);                            \
      __builtin_amdgcn_s_setprio(0);                                            \
    }                                                                           \
  }

  // prologue: stage tile 0 only
  g_stage(E,  &As[0][0], tid, m0, 0);
  g_stage(Bt, &Bs[0][0], tid, n0, 0);
  __syncthreads();                                // tile 0 landed block-wide

  for (int kt = 0; kt < 16; kt++) {
    const int cur = kt & 1;
    if (kt < 15) {
      g_stage(E,  &As[cur ^ 1][0], tid, m0, kt + 1);   // issue BEFORE compute
      g_stage(Bt, &Bs[cur ^ 1][0], tid, n0, kt + 1);   // -> flies under MFMA
    }
    COMPUTE(cur);                                 // ds_read + MFMA on cur
    __syncthreads();          // drains vmcnt (next tile) + lgkmcnt (my reads)
  }
#undef COMPUTE
#undef SWZ_OFF

  // epilogue: n even = Re, n odd = Im (adjacent lanes); p = n>>1
#pragma unroll
  for (int mi = 0; mi < 8; mi++) {
#pragma unroll
    for (int ni = 0; ni < 4; ni++) {
      int n = n0 + wn * 64 + ni * 16 + (ln & 15);
      int p = n >> 1;
      bool even = (ln & 1) == 0;
#pragma unroll
      for (int r = 0; r < 4; r++) {
        float v = acc[mi][ni][r];
        float o = __shfl_xor(v, 1, 64);
        if (even && p < PIXELS) {
          int m = m0 + wm * 128 + mi * 16 + (ln >> 4) * 4 + r;
          float s2 = (v * v + o * o) * (float)PIXELS;
          out[(size_t)m * PIXELS + p] = fminf(fmaxf(s2, 0.f), 1.f);
        }
      }
    }
  }
}

// ---------------------------------------------------------------------------
extern "C" void kernel_launch(void* const* d_in, const int* in_sizes, int n_in,
                              void* d_out, int out_size, void* d_ws, size_t ws_size,
                              hipStream_t stream) {
  const float* x    = (const float*)d_in[0];
  const float* W    = (const float*)d_in[1];
  const float* bias = (const float*)d_in[2];
  const float* qw   = (const float*)d_in[3];
  float* out        = (float*)d_out;

  char* ws = (char*)d_ws;
  f16* E  = (f16*)(ws);                                   // 16 MiB: [8192][1024]
  f16* Bt = (f16*)(ws + (size_t)16 * 1024 * 1024);        //  4 MiB: [2048][1024]
  float*    plan_mat   = (float*)(ws + (size_t)20 * 1024 * 1024);            // 25.6 KB
  unsigned* plan_idx   = (unsigned*)(ws + (size_t)20 * 1024 * 1024 + 65536); //  3.2 KB
  unsigned* plan_final = (unsigned*)(ws + (size_t)20 * 1024 * 1024 + 131072);//  40 B

  k_prep<<<dim3(1), dim3(256), 0, stream>>>(qw, plan_mat, plan_idx, plan_final);
  k_main<<<dim3(PIXELS + BATCH), dim3(256), 0, stream>>>(plan_mat, plan_idx,
                                                         plan_final, x, W, bias,
                                                         E, Bt);
  k_gemm<<<dim3(224), dim3(512), 0, stream>>>(E, Bt, out);
}

// Round 10
// 130.494 us; speedup vs baseline: 1.0438x; 1.0438x over previous
//
#include <hip/hip_runtime.h>
#include <hip/hip_bf16.h>
#include <stdint.h>

// ---------------------------------------------------------------------------
// QNN forward:
//   angles = x@W^T + b                                  (embed blocks of k_main)
//   E[b][i] = prod_w cs[w][bit_{9-w}(i)]   (product state after RY embedding)
//   Rows 0..783 of the fixed circuit unitary U, via ADJOINT simulation:
//     k_prep: build plan for U^dagger = prod_{l=19..0} [ring_l^-1 ; Rot_l^dag]
//             with CNOTs folded into GF(2) index-bit tracking and wire-pairs
//             fused into 4x4 complex matrices, pre-packed for v_pk_fma_f32.
//     k_main blocks 0..783: block p simulates U^dag|p> (100 quad passes over an
//             8KB LDS state, 256 thr, one s_barrier per pass), writes Bt rows
//             2p (Re) / 2p+1 (-Im) directly.
//     k_main blocks 784..8975: embed rows (grid filler -> hides usim latency).
//   out[b][p] = clip(|amp|^2 * 784, 0, 1)
//     -> one f16 MFMA GEMM C[8192][1664] = E @ Bt^T, 256x256 tile,
//        QUAD-BUFFERED BK=32 subtile pipeline (32 phases): per phase
//        {12 ds_read_b128 subtile k || stage subtile k+3} -> 32 MFMA ->
//        counted vmcnt(8) (2 subtiles always in flight; 0 only at tail).
//        Stage of k+3 overwrites buf of k-1, whose reads finished before the
//        phase k-1 barrier -> race-free by construction (r9's bug: 7-ahead
//        staging into a 2-tile buffer corrupted live data).
//        T2 swizzle c16 ^= (row>>1)&3 on stage source + ds_read -> 8-slot
//        spread, conflict-free. |.|^2 epilogue via shfl_xor(1), XCD swizzle.
// ---------------------------------------------------------------------------

#define NWIRES  10
#define DIM     1024
#define NLAYERS 20
#define NGATES  200
#define NPASS   100
#define PIXELS  784
#define BATCH   8192

typedef _Float16 f16;
typedef _Float16 f16x8 __attribute__((ext_vector_type(8)));
typedef float    f32x4 __attribute__((ext_vector_type(4)));
typedef float    f32x2 __attribute__((ext_vector_type(2)));

typedef const __attribute__((address_space(1))) void* gas1_t;
typedef __attribute__((address_space(3))) void*       las3_t;

__device__ __forceinline__ void gload_lds16(const void* g, void* l) {
  __builtin_amdgcn_global_load_lds((gas1_t)g, (las3_t)l, 16, 0, 0);
}

// ---------------------------------------------------------------------------
// Kernel 1: ADJOINT plan precompute (1 block).
// ---------------------------------------------------------------------------
__global__ __launch_bounds__(256) void k_prep(const float* __restrict__ qw,
                                              float* __restrict__ plan_mat,
                                              unsigned* __restrict__ plan_idx,
                                              unsigned* __restrict__ plan_final) {
  __shared__ float gm[NGATES][8];   // adjoint Rot matrices (complex 2x2)
  const int tid = threadIdx.x;

  // Rot(phi,th,om)^dag entries:
  //   a00 = e^{+i(phi+om)/2} c    a01 = e^{+i(phi-om)/2} s
  //   a10 = -e^{-i(phi-om)/2} s   a11 = e^{-i(phi+om)/2} c
  if (tid < NGATES) {
    float phi = qw[tid * 3 + 0], th = qw[tid * 3 + 1], om = qw[tid * 3 + 2];
    float s, c, sa, ca, sb, cb;
    sincosf(0.5f * th, &s, &c);
    sincosf(0.5f * (phi + om), &sa, &ca);
    sincosf(0.5f * (phi - om), &sb, &cb);
    gm[tid][0] = ca * c;  gm[tid][1] = sa * c;    // a00
    gm[tid][2] = cb * s;  gm[tid][3] = sb * s;    // a01
    gm[tid][4] = -cb * s; gm[tid][5] = sb * s;    // a10
    gm[tid][6] = ca * c;  gm[tid][7] = -sa * c;   // a11
  }
  __syncthreads();

  if (tid == 0) {
    unsigned rowA[NWIRES], invc[NWIRES];
    for (int i = 0; i < NWIRES; i++) { rowA[i] = 1u << i; invc[i] = 1u << i; }
    for (int lrev = 0; lrev < NLAYERS; lrev++) {
      int l = NLAYERS - 1 - lrev;
      int r = (l % (NWIRES - 1)) + 1;
      // inverse ring: same CNOTs, applied w = 9 .. 0
      for (int w = NWIRES - 1; w >= 0; w--) {
        int c = w, t = (w + r) % NWIRES;
        int pc = 9 - c, pt = 9 - t;
        rowA[pt] ^= rowA[pc];
        invc[pc] ^= invc[pt];
      }
      for (int s = 0; s < 5; s++) {
        int w1 = 2 * s, w2 = 2 * s + 1;
        int p1 = 9 - w1, p2 = 9 - w2;
        unsigned u1 = rowA[p1], u2 = rowA[p2];
        unsigned m1 = invc[p1], m2 = invc[p2];
        // 2-row GF(2) elimination to echelon (b1 in u1 only, b2 in u2 only)
        unsigned b1 = u1 & (0u - u1);
        if (u2 & b1) u2 ^= u1;
        unsigned b2 = u2 & (0u - u2);
        if (u1 & b2) u1 ^= u2;
        unsigned bLo = (b1 < b2) ? b1 : b2;
        unsigned bHi = (b1 < b2) ? b2 : b1;
        unsigned* P = plan_idx + (size_t)(lrev * 5 + s) * 8;
        P[0] = bLo; P[1] = bHi; P[2] = u1; P[3] = u2;
        P[4] = b1;  P[5] = b2;  P[6] = m1; P[7] = m2;
      }
    }
    for (int p = 0; p < NWIRES; p++) plan_final[p] = invc[p];
  } else if (tid >= 100 && tid < 200) {
    int t = tid - 100;                 // pass index
    int lrev = t / 5, s = t % 5;
    int l = NLAYERS - 1 - lrev;
    int g1 = l * NWIRES + 2 * s, g2 = g1 + 1;
    float* K = plan_mat + (size_t)t * 64;
#pragma unroll
    for (int r = 0; r < 4; r++) {
#pragma unroll
      for (int c = 0; c < 4; c++) {
        int r1 = r >> 1, c1 = c >> 1, r2 = r & 1, c2 = c & 1;
        float ar = gm[g1][(r1 * 2 + c1) * 2], ai = gm[g1][(r1 * 2 + c1) * 2 + 1];
        float br = gm[g2][(r2 * 2 + c2) * 2], bi = gm[g2][(r2 * 2 + c2) * 2 + 1];
        float kr = ar * br - ai * bi;
        float ki = ar * bi + ai * br;
        float* e = K + (r * 4 + c) * 4;
        e[0] = kr; e[1] = kr; e[2] = -ki; e[3] = ki;   // packed for pk-FMA
      }
    }
  }
}

// ---------------------------------------------------------------------------
// Kernel 2 (fused): blocks 0..783 = usim column p; blocks 784.. = embed rows.
// ---------------------------------------------------------------------------
__global__ __launch_bounds__(256) void k_main(const float* __restrict__ plan_mat,
                                              const unsigned* __restrict__ plan_idx,
                                              const unsigned* __restrict__ plan_final,
                                              const float* __restrict__ x,
                                              const float* __restrict__ W,
                                              const float* __restrict__ bias,
                                              f16* __restrict__ E,
                                              f16* __restrict__ Bt) {
  __shared__ f32x2 st[DIM];          // usim state (8 KB)
  __shared__ float part[4][NWIRES];  // embed partials
  __shared__ float csh[NWIRES][2];   // embed cos/sin

  const int tid = threadIdx.x;

  if (blockIdx.x < PIXELS) {
    // ---------------- usim: simulate U^dag |col> ----------------
    const int col = blockIdx.x;

    for (int i = tid; i < DIM; i += 256)
      st[i] = (f32x2){i == col ? 1.f : 0.f, 0.f};
    __syncthreads();

    for (int t = 0; t < NPASS; t++) {
      const unsigned* P = plan_idx + (size_t)t * 8;
      const unsigned bLo = P[0], bHi = P[1], u1 = P[2], u2 = P[3];
      const unsigned pb1 = P[4], pb2 = P[5], m1 = P[6], m2 = P[7];
      const f32x4* Kp = (const f32x4*)(plan_mat + (size_t)t * 64);

      // coset representative: insert 0-bits at bLo,bHi, then fix both parities
      unsigned q  = (unsigned)tid;
      unsigned xx = ((q & ~(bLo - 1u)) << 1) | (q & (bLo - 1u));
      unsigned j0 = ((xx & ~(bHi - 1u)) << 1) | (xx & (bHi - 1u));
      unsigned j  = j0 ^ ((__popc(u1 & j0) & 1) ? pb1 : 0u)
                       ^ ((__popc(u2 & j0) & 1) ? pb2 : 0u);

      f32x2 v0 = st[j];
      f32x2 v1 = st[j ^ m2];
      f32x2 v2 = st[j ^ m1];
      f32x2 v3 = st[j ^ m1 ^ m2];
      f32x2 w0 = {v0.y, v0.x}, w1 = {v1.y, v1.x};
      f32x2 w2 = {v2.y, v2.x}, w3 = {v3.y, v3.x};

      f32x2 r0 = {0.f, 0.f}, r1 = {0.f, 0.f}, r2 = {0.f, 0.f}, r3 = {0.f, 0.f};
      // Kp[e] = (kr, kr, -ki, ki):  acc += (kr,kr)*v ; acc += (-ki,ki)*swap(v)
#define CM(rr, e, vv, ww)                         \
      { f32x4 kk = Kp[e];                         \
        rr += (f32x2){kk.x, kk.y} * (vv);         \
        rr += (f32x2){kk.z, kk.w} * (ww); }
      CM(r0, 0, v0, w0)  CM(r0, 1, v1, w1)  CM(r0, 2, v2, w2)  CM(r0, 3, v3, w3)
      CM(r1, 4, v0, w0)  CM(r1, 5, v1, w1)  CM(r1, 6, v2, w2)  CM(r1, 7, v3, w3)
      CM(r2, 8, v0, w0)  CM(r2, 9, v1, w1)  CM(r2, 10, v2, w2) CM(r2, 11, v3, w3)
      CM(r3, 12, v0, w0) CM(r3, 13, v1, w1) CM(r3, 14, v2, w2) CM(r3, 15, v3, w3)
#undef CM

      // In-place write of the SAME quad this thread read: disjoint across
      // threads, so no intra-pass hazard; one barrier separates passes.
      st[j]           = r0;
      st[j ^ m2]      = r1;
      st[j ^ m1]      = r2;
      st[j ^ m1 ^ m2] = r3;
      __syncthreads();
    }

    // logical amplitude i lives at storage j = XOR of inv columns of set bits;
    // U[p][i] = conj(st[j]).
    unsigned invl[NWIRES];
#pragma unroll
    for (int p = 0; p < NWIRES; p++) invl[p] = plan_final[p];

    __align__(8) f16 re4[4], im4[4];
#pragma unroll
    for (int u = 0; u < 4; u++) {
      int i = tid * 4 + u;
      unsigned j = 0;
#pragma unroll
      for (int p = 0; p < NWIRES; p++)
        if ((i >> p) & 1) j ^= invl[p];
      f32x2 v = st[j];
      re4[u] = (f16)v.x;
      im4[u] = (f16)(-v.y);
    }
    *(uint2*)(&Bt[(size_t)(2 * col) * DIM + tid * 4])     = *(const uint2*)re4;
    *(uint2*)(&Bt[(size_t)(2 * col + 1) * DIM + tid * 4]) = *(const uint2*)im4;
    return;
  }

  // ---------------- embed: linear layer + RY product state ----------------
  const int b = blockIdx.x - PIXELS;
  const float* xr = x + (size_t)b * PIXELS;

  float acc[NWIRES];
#pragma unroll
  for (int w = 0; w < NWIRES; w++) acc[w] = 0.f;

  for (int k = tid; k < PIXELS; k += 256) {
    float xv = xr[k];
#pragma unroll
    for (int w = 0; w < NWIRES; w++) acc[w] = fmaf(xv, W[w * PIXELS + k], acc[w]);
  }

#pragma unroll
  for (int w = 0; w < NWIRES; w++) {
    float v = acc[w];
#pragma unroll
    for (int off = 32; off > 0; off >>= 1) v += __shfl_xor(v, off, 64);
    acc[w] = v;
  }

  const int wv = tid >> 6, ln = tid & 63;
  if (ln == 0) {
#pragma unroll
    for (int w = 0; w < NWIRES; w++) part[wv][w] = acc[w];
  }
  __syncthreads();
  if (tid < NWIRES) {
    float a = part[0][tid] + part[1][tid] + part[2][tid] + part[3][tid] + bias[tid];
    float s, c;
    sincosf(0.5f * a, &s, &c);
    csh[tid][0] = c;
    csh[tid][1] = s;
  }
  __syncthreads();

  __align__(8) f16 e4[4];
#pragma unroll
  for (int u = 0; u < 4; u++) {
    int i = tid * 4 + u;
    float pr = 1.f;
#pragma unroll
    for (int w = 0; w < NWIRES; w++) pr *= csh[w][(i >> (9 - w)) & 1];
    e4[u] = (f16)pr;
  }
  *(uint2*)(&E[(size_t)b * DIM + tid * 4]) = *(const uint2*)e4;
}

// ---------------------------------------------------------------------------
// Kernel 3: C = E[8192][1024] @ Bt^T, f16 MFMA 16x16x32.
// 256x256 tile, 512 threads (8 waves, 2M x 4N).
// QUAD-BUFFERED BK=32 subtile pipeline, 32 phases:
//   phase k: ds_read subtile k (buf k&3: 8 af + 4 bf b128) || stage subtile
//   k+3 into buf (k+3)&3 (4 gload_lds) -> 32 MFMA -> vmcnt(8) -> s_barrier.
//   Capacity proof: buf (k+3)&3 holds subtile k-1, whose ds_reads completed
//   before phase k-1's barrier (MFMA operands force lgkmcnt) -> no race.
//   vmcnt ledger: 12 loads outstanding steady-state; vmcnt(8) lands subtile
//   k+1; tail k=29: vmcnt(4), k=30: vmcnt(0).
// Swizzle: c16 ^= (row>>1)&3 on stage source + ds_read -> lanes spread over
// all 8 16B-slot-columns (8 rows each) = conflict-free.
// Fused |re|^2+|im|^2 epilogue; XCD-swizzled flat grid (224 = 8 x 28).
// ---------------------------------------------------------------------------
__global__ __launch_bounds__(512, 2) void k_gemm(const f16* __restrict__ E,
                                                 const f16* __restrict__ Bt,
                                                 float* __restrict__ out) {
  __shared__ __align__(16) f16 As[4][256 * 32];   // 64 KB
  __shared__ __align__(16) f16 Bs[4][256 * 32];   // 64 KB

  const int tid = threadIdx.x;                    // 0..511
  const int wid = tid >> 6, ln = tid & 63;
  const int wm = wid >> 2, wn = wid & 3;          // 2 x 4 wave grid

  const int bid = blockIdx.x;                     // 0..223 (32 mt x 7 nt)
  const int swz = (bid & 7) * 28 + (bid >> 3);    // XCD-contiguous chunks
  const int mt  = swz % 32, nt = swz / 32;
  const int m0  = mt * 256;
  const int n0  = nt * 256;

  f32x4 acc[8][4];
#pragma unroll
  for (int a = 0; a < 8; a++)
#pragma unroll
    for (int q = 0; q < 4; q++) acc[a][q] = (f32x4){0.f, 0.f, 0.f, 0.f};

  // per-lane swizzled ds_read element offsets within a 256x32 subtile
  int offA[8], offB[4];
#pragma unroll
  for (int mi = 0; mi < 8; mi++) {
    int Ra = wm * 128 + mi * 16 + (ln & 15);
    offA[mi] = Ra * 32 + (((ln >> 4) ^ ((Ra >> 1) & 3)) * 8);
  }
#pragma unroll
  for (int ni = 0; ni < 4; ni++) {
    int Rb = wn * 64 + ni * 16 + (ln & 15);
    offB[ni] = Rb * 32 + (((ln >> 4) ^ ((Rb >> 1) & 3)) * 8);
  }

  // stage subtile t (A 256x32 + B 256x32) into buf t&3; 4 gload_lds/thread.
  auto stage = [&](int t) {
    const int sb = t & 3;
#pragma unroll
    for (int r = 0; r < 2; r++) {
      int u   = r * 512 + tid;                // 16B unit, 0..1023 (linear LDS)
      int row = u >> 2;
      int c16 = (u & 3) ^ ((row >> 1) & 3);   // inverse-swizzled source col
      gload_lds16((const char*)E + (size_t)(m0 + row) * 2048 + t * 64 + c16 * 16,
                  (char*)&As[sb][0] + (size_t)u * 16);
    }
#pragma unroll
    for (int r = 0; r < 2; r++) {
      int u   = r * 512 + tid;
      int row = u >> 2;
      int c16 = (u & 3) ^ ((row >> 1) & 3);
      gload_lds16((const char*)Bt + (size_t)(n0 + row) * 2048 + t * 64 + c16 * 16,
                  (char*)&Bs[sb][0] + (size_t)u * 16);
    }
  };

  // prologue: subtiles 0,1,2 in flight (12 loads/wave)
  stage(0);
  stage(1);
  stage(2);
  asm volatile("s_waitcnt vmcnt(8)" ::: "memory");   // subtile 0 landed
  __builtin_amdgcn_s_barrier();

#pragma unroll 4
  for (int k = 0; k < 32; k++) {
    const int buf = k & 3;
    f16x8 af[8], bf[4];
#pragma unroll
    for (int mi = 0; mi < 8; mi++) af[mi] = *(const f16x8*)&As[buf][offA[mi]];
#pragma unroll
    for (int ni = 0; ni < 4; ni++) bf[ni] = *(const f16x8*)&Bs[buf][offB[ni]];

    if (k < 29) stage(k + 3);                 // writes buf of subtile k-1 (free)

    __builtin_amdgcn_s_setprio(1);
#pragma unroll
    for (int mi = 0; mi < 8; mi++)
#pragma unroll
      for (int ni = 0; ni < 4; ni++)
        acc[mi][ni] = __builtin_amdgcn_mfma_f32_16x16x32_f16(
            af[mi], bf[ni], acc[mi][ni], 0, 0, 0);
    __builtin_amdgcn_s_setprio(0);

    if (k < 29)       { asm volatile("s_waitcnt vmcnt(8)" ::: "memory"); }
    else if (k == 29) { asm volatile("s_waitcnt vmcnt(4)" ::: "memory"); }
    else if (k == 30) { asm volatile("s_waitcnt vmcnt(0)" ::: "memory"); }
    __builtin_amdgcn_s_barrier();
  }

  // epilogue: n even = Re, n odd = Im (adjacent lanes); p = n>>1
#pragma unroll
  for (int mi = 0; mi < 8; mi++) {
#pragma unroll
    for (int ni = 0; ni < 4; ni++) {
      int n = n0 + wn * 64 + ni * 16 + (ln & 15);
      int p = n >> 1;
      bool even = (ln & 1) == 0;
#pragma unroll
      for (int r = 0; r < 4; r++) {
        float v = acc[mi][ni][r];
        float o = __shfl_xor(v, 1, 64);
        if (even && p < PIXELS) {
          int m = m0 + wm * 128 + mi * 16 + (ln >> 4) * 4 + r;
          float s2 = (v * v + o * o) * (float)PIXELS;
          out[(size_t)m * PIXELS + p] = fminf(fmaxf(s2, 0.f), 1.f);
        }
      }
    }
  }
}

// ---------------------------------------------------------------------------
extern "C" void kernel_launch(void* const* d_in, const int* in_sizes, int n_in,
                              void* d_out, int out_size, void* d_ws, size_t ws_size,
                              hipStream_t stream) {
  const float* x    = (const float*)d_in[0];
  const float* W    = (const float*)d_in[1];
  const float* bias = (const float*)d_in[2];
  const float* qw   = (const float*)d_in[3];
  float* out        = (float*)d_out;

  char* ws = (char*)d_ws;
  f16* E  = (f16*)(ws);                                   // 16 MiB: [8192][1024]
  f16* Bt = (f16*)(ws + (size_t)16 * 1024 * 1024);        //  4 MiB: [2048][1024]
  float*    plan_mat   = (float*)(ws + (size_t)20 * 1024 * 1024);            // 25.6 KB
  unsigned* plan_idx   = (unsigned*)(ws + (size_t)20 * 1024 * 1024 + 65536); //  3.2 KB
  unsigned* plan_final = (unsigned*)(ws + (size_t)20 * 1024 * 1024 + 131072);//  40 B

  k_prep<<<dim3(1), dim3(256), 0, stream>>>(qw, plan_mat, plan_idx, plan_final);
  k_main<<<dim3(PIXELS + BATCH), dim3(256), 0, stream>>>(plan_mat, plan_idx,
                                                         plan_final, x, W, bias,
                                                         E, Bt);
  k_gemm<<<dim3(224), dim3(512), 0, stream>>>(E, Bt, out);
}